// Round 2
// baseline (633.230 us; speedup 1.0000x reference)
//
#include <hip/hip_runtime.h>

#define NCLS 19
#define NIMG 16
#define HW (512 * 512)
#define EPSV 1e-6f

// ---------------------------------------------------------------------------
// Kernel 1: per-pixel argmax over C for preds & targets, histogram into
// per-(image,class) counters: pred_cnt, targ_cnt, inter.
// Each thread handles 4 consecutive pixels via float4 loads. All 19 class
// loads are issued into a register array BEFORE any compare so the wave keeps
// 19 outstanding global_load_dwordx4 (max MLP). 32-bit offsets only.
// ---------------------------------------------------------------------------
__global__ __launch_bounds__(256, 4) void hist_kernel(
    const float* __restrict__ preds, const float* __restrict__ targs,
    int* __restrict__ gpred, int* __restrict__ gtarg, int* __restrict__ ginter)
{
    __shared__ int s_pred[NCLS];
    __shared__ int s_targ[NCLS];
    __shared__ int s_inter[NCLS];

    const int t = threadIdx.x;
    if (t < NCLS) { s_pred[t] = 0; s_targ[t] = 0; s_inter[t] = 0; }
    __syncthreads();

    const int n = blockIdx.y;
    const unsigned pix = blockIdx.x * 1024u + (unsigned)t * 4u;  // 4 px/thread
    // image base: n * 19 * 256K < 80M elements -> fits 32-bit
    const float* __restrict__ pimg = preds + (unsigned)n * (NCLS * HW) + pix;
    const float* __restrict__ timg = targs + (unsigned)n * (NCLS * HW) + pix;

    // ---- phase 1: preds — load all 19 planes, then argmax (strict >)
    float4 u[NCLS];
#pragma unroll
    for (int c = 0; c < NCLS; ++c) u[c] = *(const float4*)(pimg + c * HW);

    float m0 = u[0].x, m1 = u[0].y, m2 = u[0].z, m3 = u[0].w;
    int   a0 = 0, a1 = 0, a2 = 0, a3 = 0;
#pragma unroll
    for (int c = 1; c < NCLS; ++c) {
        if (u[c].x > m0) { m0 = u[c].x; a0 = c; }
        if (u[c].y > m1) { m1 = u[c].y; a1 = c; }
        if (u[c].z > m2) { m2 = u[c].z; a2 = c; }
        if (u[c].w > m3) { m3 = u[c].w; a3 = c; }
    }

    // ---- phase 2: targets
#pragma unroll
    for (int c = 0; c < NCLS; ++c) u[c] = *(const float4*)(timg + c * HW);

    float q0 = u[0].x, q1 = u[0].y, q2 = u[0].z, q3 = u[0].w;
    int   b0 = 0, b1 = 0, b2 = 0, b3 = 0;
#pragma unroll
    for (int c = 1; c < NCLS; ++c) {
        if (u[c].x > q0) { q0 = u[c].x; b0 = c; }
        if (u[c].y > q1) { q1 = u[c].y; b1 = c; }
        if (u[c].z > q2) { q2 = u[c].z; b2 = c; }
        if (u[c].w > q3) { q3 = u[c].w; b3 = c; }
    }

    // ---- LDS histogram (12 atomics/thread; compute-cheap vs 100us mem floor)
    atomicAdd(&s_pred[a0], 1); atomicAdd(&s_targ[b0], 1); if (a0 == b0) atomicAdd(&s_inter[a0], 1);
    atomicAdd(&s_pred[a1], 1); atomicAdd(&s_targ[b1], 1); if (a1 == b1) atomicAdd(&s_inter[a1], 1);
    atomicAdd(&s_pred[a2], 1); atomicAdd(&s_targ[b2], 1); if (a2 == b2) atomicAdd(&s_inter[a2], 1);
    atomicAdd(&s_pred[a3], 1); atomicAdd(&s_targ[b3], 1); if (a3 == b3) atomicAdd(&s_inter[a3], 1);
    __syncthreads();

    // ---- one global atomic per bin per block (device-scope, XCD-safe)
    if (t < NCLS) {
        atomicAdd(&gpred [n * NCLS + t], s_pred [t]);
        atomicAdd(&gtarg [n * NCLS + t], s_targ [t]);
        atomicAdd(&ginter[n * NCLS + t], s_inter[t]);
    }
}

// ---------------------------------------------------------------------------
// Kernel 2: IoU per (n,c), weighted mean -> scalar.
// ---------------------------------------------------------------------------
__global__ __launch_bounds__(256) void finalize_kernel(
    const int* __restrict__ gpred, const int* __restrict__ gtarg,
    const int* __restrict__ ginter, const float* __restrict__ wts,
    float* __restrict__ out)
{
    const int t = threadIdx.x;
    float sum = 0.f;
    for (int i = t; i < NIMG * NCLS; i += 256) {
        const int c  = i % NCLS;
        const float ic = (float)ginter[i];
        const float un = (float)gpred[i] + (float)gtarg[i] - ic;
        sum += wts[c] * (ic + EPSV) / (un + EPSV);
    }
#pragma unroll
    for (int off = 32; off > 0; off >>= 1) sum += __shfl_down(sum, off, 64);

    __shared__ float wsum[4];
    if ((t & 63) == 0) wsum[t >> 6] = sum;
    __syncthreads();
    if (t == 0) {
        out[0] = (wsum[0] + wsum[1] + wsum[2] + wsum[3]) / (float)(NIMG * NCLS);
    }
}

extern "C" void kernel_launch(void* const* d_in, const int* in_sizes, int n_in,
                              void* d_out, int out_size, void* d_ws, size_t ws_size,
                              hipStream_t stream) {
    const float* preds = (const float*)d_in[0];
    const float* targs = (const float*)d_in[1];
    const float* wts   = (const float*)d_in[2];
    float* out = (float*)d_out;

    int* gpred  = (int*)d_ws;
    int* gtarg  = gpred + NIMG * NCLS;
    int* ginter = gtarg + NIMG * NCLS;

    // ws is re-poisoned to 0xAA before every timed launch -> zero our 3.6 KB.
    hipMemsetAsync(d_ws, 0, 3 * NIMG * NCLS * sizeof(int), stream);

    dim3 grid(HW / 1024, NIMG);  // 256 blocks/image * 16 images = 4096 blocks
    hist_kernel<<<grid, 256, 0, stream>>>(preds, targs, gpred, gtarg, ginter);
    finalize_kernel<<<1, 256, 0, stream>>>(gpred, gtarg, ginter, wts, out);
}